// Round 5
// baseline (2286.015 us; speedup 1.0000x reference)
//
#include <hip/hip_runtime.h>
#include <hip/hip_bf16.h>
#include <cstdint>
#include <cstddef>

typedef _Float16 half8 __attribute__((ext_vector_type(8)));
typedef _Float16 half4 __attribute__((ext_vector_type(4)));
typedef float floatx4 __attribute__((ext_vector_type(4)));

#define B_ 256
#define T_ 168
#define H_ 1024
#define WS_ 64
#define LAG_ 168
#define LAT_ 128

__device__ __forceinline__ float fast_sigmoid(float x) {
    return __builtin_amdgcn_rcpf(1.f + __expf(-x));
}
__device__ __forceinline__ float fast_tanh(float x) {
    // 1 - 2/(e^{2x}+1); exp->inf and ->0 limits both correct
    return 1.f - 2.f * __builtin_amdgcn_rcpf(__expf(2.f * x) + 1.f);
}

// ---------------- fp32 -> fp16 conversion (vectorized x4) ----------------
__global__ void cvt_f32_f16_v4(const float4* __restrict__ src, half4* __restrict__ dst, int n4) {
    int i = blockIdx.x * blockDim.x + threadIdx.x;
    if (i < n4) {
        float4 v = src[i];
        half4 o;
        o[0] = (_Float16)v.x; o[1] = (_Float16)v.y;
        o[2] = (_Float16)v.z; o[3] = (_Float16)v.w;
        dst[i] = o;
    }
}

// ---------------- encoder layers 1,2: leaky(in @ W^T + b) ----------------
__global__ void enc12(const float* __restrict__ in, const float* __restrict__ W,
                      const float* __restrict__ bias, float* __restrict__ outb, int infeat) {
    int r = blockIdx.x, j = threadIdx.x;
    const float* row = in + (size_t)r * infeat;
    const float* w   = W  + (size_t)j * infeat;
    float s = bias[j];
    for (int k = 0; k < infeat; ++k) s += row[k] * w[k];
    outb[(size_t)r * blockDim.x + j] = (s >= 0.f) ? s : 0.01f * s;
}

// ---------------- encoder layer 3: h0 = h2 @ W3^T + b3 ----------------
__global__ void enc3(const float* __restrict__ h2, const float* __restrict__ W3,
                     const float* __restrict__ b3, float* __restrict__ hprev32,
                     _Float16* __restrict__ h0f16) {
    __shared__ float s[LAT_];
    int r = blockIdx.x;
    if (threadIdx.x < LAT_) s[threadIdx.x] = h2[(size_t)r * LAT_ + threadIdx.x];
    __syncthreads();
    for (int j = threadIdx.x; j < H_; j += 256) {
        const float* w = W3 + (size_t)j * LAT_;
        float acc = b3[j];
        #pragma unroll 8
        for (int k = 0; k < LAT_; ++k) acc += s[k] * w[k];
        hprev32[(size_t)r * H_ + j] = acc;
        h0f16[(size_t)r * H_ + j]   = (_Float16)acc;
    }
}

// ---------------- persistent GRU ----------------
// grid 512 x 128 thr (2 waves), 2 WGs/CU (LDS 48KB, 1 wave/SIMD via launch_bounds).
// qi = blk&31 -> units [32qi,+32); pi = blk>>5 -> rows [16pi,+16).
// wave w owns units [32qi+16w,+16) x 3 gates. r,z Whh resident in VGPRs (256);
// n-gate prefetched each step before h staging (latency hidden, L2-fed).
// h exchange: agent-scope 8B atomics; per-pi 32-WG monotonic barrier.
__global__ __launch_bounds__(128, 1) void gru_persistent(
    _Float16* __restrict__ hb0, _Float16* __restrict__ hb1,
    const float* __restrict__ hprev32, const _Float16* __restrict__ whh16,
    const _Float16* __restrict__ wih16, const _Float16* __restrict__ x16,
    const float* __restrict__ bih, const float* __restrict__ bhh,
    const float* __restrict__ Wo, float* __restrict__ partials,
    unsigned* __restrict__ bar)
{
    __shared__ __align__(16) _Float16 Ash[16 * 1032];   // 16 h-rows x 1024k (+8 pad) = 33 KB
    __shared__ __align__(16) _Float16 Wsh[96 * 72];     // Wih slice: 96 gate-cols x 64k (+8) = 13.8 KB
    __shared__ __align__(16) _Float16 Hsh[512];         // h-out transpose: 16 rows x 32 units

    const int tid  = threadIdx.x;
    const int w    = tid >> 6;
    const int lane = tid & 63;
    const int m16  = lane & 15;
    const int quad = lane >> 4;
    const int qi   = blockIdx.x & 31;
    const int pi   = blockIdx.x >> 5;
    const int pi16 = pi << 4;
    const int u    = (qi << 5) + (w << 4) + m16;

    // Wih slice -> LDS (once): 96 rows x 8 uint4
    for (int idx = tid; idx < 768; idx += 128) {
        int rowl = idx >> 3, ch = idx & 7;
        int g = rowl >> 5, ru = rowl & 31;
        *(uint4*)(&Wsh[rowl * 72 + (ch << 3)]) =
            *(const uint4*)(wih16 + (size_t)(((g << 10) + (qi << 5) + ru) << 6) + (ch << 3));
    }

    // Resident Whh fragments: r,z gates (64 frags = 256 VGPR)
    half8 br[32], bz[32];
    {
        const _Float16* p0 = whh16 + ((size_t)u << 10) + (quad << 3);
        const _Float16* p1 = whh16 + ((size_t)(H_ + u) << 10) + (quad << 3);
        #pragma unroll
        for (int c = 0; c < 32; ++c) br[c] = *(const half8*)(p0 + (c << 5));
        #pragma unroll
        for (int c = 0; c < 32; ++c) bz[c] = *(const half8*)(p1 + (c << 5));
    }
    const _Float16* bnp = whh16 + ((size_t)(2 * H_ + u) << 10) + (quad << 3);

    const float b_r  = bih[u]          + bhh[u];
    const float b_z  = bih[H_ + u]     + bhh[H_ + u];
    const float b_in = bih[2 * H_ + u];
    const float b_hn = bhh[2 * H_ + u];
    const float wo_u = Wo[u];

    float hreg[4];
    #pragma unroll
    for (int i = 0; i < 4; ++i)
        hreg[i] = hprev32[((size_t)(pi16 + (quad << 2) + i) << 10) + u];

    __syncthreads();

    unsigned* cnt = bar + pi * 32;          // monotonic arrival counter (per pi-group, 32 WGs)
    unsigned* gen = bar + 512 + pi * 32;    // published generation

    for (int t = 0; t < T_; ++t) {
        const _Float16* hsrc = (t & 1) ? hb1 : hb0;
        _Float16*       hdst = (t & 1) ? hb0 : hb1;

        // ---- h-independent prefetch: n-gate B-frags + x fragment (L2-latency hides
        //      behind the h staging + barrier-adjacent work) ----
        half8 bn[32];
        #pragma unroll
        for (int c = 0; c < 32; ++c) bn[c] = *(const half8*)(bnp + (c << 5));
        half8 ax0 = *(const half8*)(x16 + (((size_t)t << 8) + pi16 + m16) * WS_ + (quad << 3));
        half8 ax1 = *(const half8*)(x16 + (((size_t)t << 8) + pi16 + m16) * WS_ + 32 + (quad << 3));

        // ---- stage h rows via agent-coherent 8B loads (bypass stale L1/L2) ----
        #pragma unroll
        for (int it = 0; it < 32; ++it) {
            int idx = tid + (it << 7);
            int row = idx >> 8, k4 = idx & 255;
            unsigned long long v = __hip_atomic_load(
                (const unsigned long long*)(hsrc + ((size_t)(pi16 + row) << 10) + (k4 << 2)),
                __ATOMIC_RELAXED, __HIP_MEMORY_SCOPE_AGENT);
            *(unsigned long long*)(&Ash[row * 1032 + (k4 << 2)]) = v;
        }
        __syncthreads();

        floatx4 acc_r  = {b_r,  b_r,  b_r,  b_r };
        floatx4 acc_z  = {b_z,  b_z,  b_z,  b_z };
        floatx4 acc_in = {b_in, b_in, b_in, b_in};
        floatx4 acc_hn = {b_hn, b_hn, b_hn, b_hn};

        // gi = x_t @ Wih^T (K=64, Wih from LDS)
        {
            half8 p0 = *(const half8*)(&Wsh[((w << 4) + m16) * 72       + (quad << 3)]);
            half8 p1 = *(const half8*)(&Wsh[(32 + (w << 4) + m16) * 72  + (quad << 3)]);
            half8 p2 = *(const half8*)(&Wsh[(64 + (w << 4) + m16) * 72  + (quad << 3)]);
            acc_r  = __builtin_amdgcn_mfma_f32_16x16x32_f16(ax0, p0, acc_r,  0, 0, 0);
            acc_z  = __builtin_amdgcn_mfma_f32_16x16x32_f16(ax0, p1, acc_z,  0, 0, 0);
            acc_in = __builtin_amdgcn_mfma_f32_16x16x32_f16(ax0, p2, acc_in, 0, 0, 0);
            half8 q0 = *(const half8*)(&Wsh[((w << 4) + m16) * 72       + 32 + (quad << 3)]);
            half8 q1 = *(const half8*)(&Wsh[(32 + (w << 4) + m16) * 72  + 32 + (quad << 3)]);
            half8 q2 = *(const half8*)(&Wsh[(64 + (w << 4) + m16) * 72  + 32 + (quad << 3)]);
            acc_r  = __builtin_amdgcn_mfma_f32_16x16x32_f16(ax1, q0, acc_r,  0, 0, 0);
            acc_z  = __builtin_amdgcn_mfma_f32_16x16x32_f16(ax1, q1, acc_z,  0, 0, 0);
            acc_in = __builtin_amdgcn_mfma_f32_16x16x32_f16(ax1, q2, acc_in, 0, 0, 0);
        }

        // gh = h @ Whh^T (K=1024): r,z resident, n prefetched
        #pragma unroll
        for (int c = 0; c < 32; ++c) {
            half8 a = *(const half8*)(&Ash[m16 * 1032 + (c << 5) + (quad << 3)]);
            acc_r  = __builtin_amdgcn_mfma_f32_16x16x32_f16(a, br[c], acc_r,  0, 0, 0);
            acc_z  = __builtin_amdgcn_mfma_f32_16x16x32_f16(a, bz[c], acc_z,  0, 0, 0);
            acc_hn = __builtin_amdgcn_mfma_f32_16x16x32_f16(a, bn[c], acc_hn, 0, 0, 0);
        }

        // GRU nonlinearity; h stays in registers
        float pv[4];
        #pragma unroll
        for (int i = 0; i < 4; ++i) {
            float rg = fast_sigmoid(acc_r[i]);
            float zg = fast_sigmoid(acc_z[i]);
            float ng = fast_tanh(acc_in[i] + rg * acc_hn[i]);
            float hn2 = (1.f - zg) * ng + zg * hreg[i];
            hreg[i] = hn2;
            pv[i] = hn2 * wo_u;
            Hsh[((quad << 2) + i) * 32 + (w << 4) + m16] = (_Float16)hn2;
        }
        #pragma unroll
        for (int m = 1; m < 16; m <<= 1) {
            #pragma unroll
            for (int i = 0; i < 4; ++i) pv[i] += __shfl_xor(pv[i], m);
        }
        if (m16 == 0) {
            #pragma unroll
            for (int i = 0; i < 4; ++i)
                partials[((size_t)t * B_ + pi16 + (quad << 2) + i) * 64 + (qi << 1) + w] = pv[i];
        }
        __syncthreads();

        // publish h16: 128 thr x 8B via agent-coherent store
        {
            unsigned long long hv = *(const unsigned long long*)(&Hsh[tid << 2]);
            __hip_atomic_store(
                (unsigned long long*)(hdst + ((size_t)(pi16 + (tid >> 3)) << 10) + (qi << 5) + ((tid & 7) << 2)),
                hv, __ATOMIC_RELAXED, __HIP_MEMORY_SCOPE_AGENT);
        }

        if (t < T_ - 1) {
            asm volatile("s_waitcnt vmcnt(0)" ::: "memory");  // h stores at coherence point
            __syncthreads();                                   // both waves drained
            if (tid == 0) {
                unsigned old = __hip_atomic_fetch_add(cnt, 1u, __ATOMIC_RELAXED, __HIP_MEMORY_SCOPE_AGENT);
                if (old == (unsigned)(32 * (t + 1) - 1)) {
                    __hip_atomic_store(gen, (unsigned)(t + 1), __ATOMIC_RELAXED, __HIP_MEMORY_SCOPE_AGENT);
                } else {
                    while (__hip_atomic_load(gen, __ATOMIC_RELAXED, __HIP_MEMORY_SCOPE_AGENT) < (unsigned)(t + 1))
                        __builtin_amdgcn_s_sleep(2);
                }
            }
            __syncthreads();
        }
    }
}

// ---------------- final: out[r,t] = sum_q partials[t,r,q] + bo ----------------
__global__ void out_reduce(const float* __restrict__ partials, const float* __restrict__ bo,
                           float* __restrict__ out) {
    int t = blockIdx.x, r = threadIdx.x;
    const float* p = partials + ((size_t)t * B_ + r) * 64;
    float s = 0.f;
    #pragma unroll
    for (int i = 0; i < 64; ++i) s += p[i];
    out[(size_t)r * T_ + t] = s + bo[0];
}

extern "C" void kernel_launch(void* const* d_in, const int* in_sizes, int n_in,
                              void* d_out, int out_size, void* d_ws, size_t ws_size,
                              hipStream_t stream) {
    const float* lag  = (const float*)d_in[0];
    const float* curr = (const float*)d_in[1];
    const float* W1   = (const float*)d_in[2];
    const float* b1   = (const float*)d_in[3];
    const float* W2   = (const float*)d_in[4];
    const float* b2   = (const float*)d_in[5];
    const float* W3   = (const float*)d_in[6];
    const float* b3   = (const float*)d_in[7];
    const float* Wih  = (const float*)d_in[8];
    const float* Whh  = (const float*)d_in[9];
    const float* bih  = (const float*)d_in[10];
    const float* bhh  = (const float*)d_in[11];
    const float* Wo   = (const float*)d_in[12];
    const float* bo   = (const float*)d_in[13];
    float* out = (float*)d_out;

    char* ws = (char*)d_ws;
    size_t off = 0;
    auto alloc = [&](size_t bytes) -> void* {
        void* p = ws + off;
        off += (bytes + 255) & ~(size_t)255;
        return p;
    };
    _Float16* whh16 = (_Float16*)alloc((size_t)3 * H_ * H_ * 2);
    _Float16* wih16 = (_Float16*)alloc((size_t)3 * H_ * WS_ * 2);
    _Float16* x16   = (_Float16*)alloc((size_t)T_ * B_ * WS_ * 2);
    _Float16* hb0   = (_Float16*)alloc((size_t)B_ * H_ * 2);
    _Float16* hb1   = (_Float16*)alloc((size_t)B_ * H_ * 2);
    float* hprev32  = (float*)alloc((size_t)B_ * H_ * 4);
    float* h1       = (float*)alloc((size_t)B_ * 64 * 4);
    float* h2       = (float*)alloc((size_t)B_ * LAT_ * 4);
    float* partials = (float*)alloc((size_t)T_ * B_ * 64 * 4);
    unsigned* bar   = (unsigned*)alloc(1024 * 4);

    hipMemsetAsync(bar, 0, 1024 * 4, stream);

    int n4;
    n4 = 3 * H_ * H_ / 4;
    cvt_f32_f16_v4<<<(n4 + 255) / 256, 256, 0, stream>>>((const float4*)Whh, (half4*)whh16, n4);
    n4 = 3 * H_ * WS_ / 4;
    cvt_f32_f16_v4<<<(n4 + 255) / 256, 256, 0, stream>>>((const float4*)Wih, (half4*)wih16, n4);
    n4 = T_ * B_ * WS_ / 4;
    cvt_f32_f16_v4<<<(n4 + 255) / 256, 256, 0, stream>>>((const float4*)curr, (half4*)x16, n4);

    enc12<<<B_, 64, 0, stream>>>(lag, W1, b1, h1, LAG_);
    enc12<<<B_, LAT_, 0, stream>>>(h1, W2, b2, h2, 64);
    enc3<<<B_, 256, 0, stream>>>(h2, W3, b3, hprev32, hb0);

    gru_persistent<<<dim3(512), dim3(128), 0, stream>>>(
        hb0, hb1, hprev32, whh16, wih16, x16, bih, bhh, Wo, partials, bar);

    out_reduce<<<T_, B_, 0, stream>>>(partials, bo, out);
}

// Round 6
// 1515.212 us; speedup vs baseline: 1.5087x; 1.5087x over previous
//
#include <hip/hip_runtime.h>
#include <hip/hip_bf16.h>
#include <cstdint>
#include <cstddef>

typedef _Float16 half8 __attribute__((ext_vector_type(8)));
typedef _Float16 half4 __attribute__((ext_vector_type(4)));
typedef float floatx4 __attribute__((ext_vector_type(4)));

#define B_ 256
#define T_ 168
#define H_ 1024
#define WS_ 64
#define LAG_ 168
#define LAT_ 128

__device__ __forceinline__ float fast_sigmoid(float x) {
    return __builtin_amdgcn_rcpf(1.f + __expf(-x));
}
__device__ __forceinline__ float fast_tanh(float x) {
    return 1.f - 2.f * __builtin_amdgcn_rcpf(__expf(2.f * x) + 1.f);
}

// ---------------- fp32 -> fp16 conversion (vectorized x4) ----------------
__global__ void cvt_f32_f16_v4(const float4* __restrict__ src, half4* __restrict__ dst, int n4) {
    int i = blockIdx.x * blockDim.x + threadIdx.x;
    if (i < n4) {
        float4 v = src[i];
        half4 o;
        o[0] = (_Float16)v.x; o[1] = (_Float16)v.y;
        o[2] = (_Float16)v.z; o[3] = (_Float16)v.w;
        dst[i] = o;
    }
}

// ---------------- encoder layers 1,2: leaky(in @ W^T + b) ----------------
__global__ void enc12(const float* __restrict__ in, const float* __restrict__ W,
                      const float* __restrict__ bias, float* __restrict__ outb, int infeat) {
    int r = blockIdx.x, j = threadIdx.x;
    const float* row = in + (size_t)r * infeat;
    const float* w   = W  + (size_t)j * infeat;
    float s = bias[j];
    for (int k = 0; k < infeat; ++k) s += row[k] * w[k];
    outb[(size_t)r * blockDim.x + j] = (s >= 0.f) ? s : 0.01f * s;
}

// ---------------- encoder layer 3: h0 = h2 @ W3^T + b3 ----------------
__global__ void enc3(const float* __restrict__ h2, const float* __restrict__ W3,
                     const float* __restrict__ b3, float* __restrict__ hprev32,
                     _Float16* __restrict__ h0f16) {
    __shared__ float s[LAT_];
    int r = blockIdx.x;
    if (threadIdx.x < LAT_) s[threadIdx.x] = h2[(size_t)r * LAT_ + threadIdx.x];
    __syncthreads();
    for (int j = threadIdx.x; j < H_; j += 256) {
        const float* w = W3 + (size_t)j * LAT_;
        float acc = b3[j];
        #pragma unroll 8
        for (int k = 0; k < LAT_; ++k) acc += s[k] * w[k];
        hprev32[(size_t)r * H_ + j] = acc;
        h0f16[(size_t)r * H_ + j]   = (_Float16)acc;
    }
}

// ---------------- persistent GRU: dataflow-flag exchange ----------------
// 256 WGs x 256 thr (R4 shape): pi=blk&15 rows [16pi,+16); qi=blk>>4 units [64qi,+64).
// r,z Whh resident (256 regs, AGPR-backed); n-gate streamed double-buffered 8+8.
// h in 4-deep ring of fp16 buffers. Producer: publish 2KB slice -> vmcnt drain ->
// flag[pi][qi]=t+1 (own 64B line, agent store). Consumer: per-wave parallel flag
// gather; stage each ready slice immediately (fine-grained, absorbs skew).
__global__ __launch_bounds__(256, 1) void gru_persistent(
    _Float16* __restrict__ hbuf,           // 4 x [B,H] ring
    const float* __restrict__ hprev32, const _Float16* __restrict__ whh16,
    const _Float16* __restrict__ wih16, const _Float16* __restrict__ x16,
    const float* __restrict__ bih, const float* __restrict__ bhh,
    const float* __restrict__ Wo, float* __restrict__ partials,
    unsigned* __restrict__ bar)            // flags: [(pi*16+qi)*16] u32, 64B stride
{
    __shared__ __align__(16) _Float16 Ash[16 * 1032];   // 16 h-rows x 1024k (+8 pad)
    __shared__ __align__(16) _Float16 Wsh[192 * 72];    // Wih slice
    __shared__ __align__(16) _Float16 Hsh[1024];        // h-out transpose

    const int tid  = threadIdx.x;
    const int w    = tid >> 6;
    const int lane = tid & 63;
    const int m16  = lane & 15;
    const int quad = lane >> 4;
    const int pi   = blockIdx.x & 15;
    const int qi   = blockIdx.x >> 4;
    const int pi16 = pi << 4;
    const int u    = (qi << 6) + (w << 4) + m16;

    // Wih slice -> LDS (once)
    for (int idx = tid; idx < 1536; idx += 256) {
        int rowl = idx >> 3, ch = idx & 7;
        int g = rowl >> 6, ru = rowl & 63;
        *(uint4*)(&Wsh[rowl * 72 + (ch << 3)]) =
            *(const uint4*)(wih16 + (size_t)(((g << 10) + (qi << 6) + ru) << 6) + (ch << 3));
    }

    // Resident Whh fragments: r,z gates (64 frags; compiler backs with AGPRs)
    half8 br[32], bz[32];
    {
        const _Float16* p0 = whh16 + ((size_t)u << 10) + (quad << 3);
        const _Float16* p1 = whh16 + ((size_t)(H_ + u) << 10) + (quad << 3);
        #pragma unroll
        for (int c = 0; c < 32; ++c) br[c] = *(const half8*)(p0 + (c << 5));
        #pragma unroll
        for (int c = 0; c < 32; ++c) bz[c] = *(const half8*)(p1 + (c << 5));
    }
    const _Float16* bnp = whh16 + ((size_t)(2 * H_ + u) << 10) + (quad << 3);

    const float b_r  = bih[u]          + bhh[u];
    const float b_z  = bih[H_ + u]     + bhh[H_ + u];
    const float b_in = bih[2 * H_ + u];
    const float b_hn = bhh[2 * H_ + u];
    const float wo_u = Wo[u];

    float hreg[4];
    #pragma unroll
    for (int i = 0; i < 4; ++i)
        hreg[i] = hprev32[((size_t)(pi16 + (quad << 2) + i) << 10) + u];

    __syncthreads();

    unsigned* flag_self = bar + (((pi << 4) | qi) << 4);
    // staging assignment: wave w stages rows [4w, 4w+4); lane -> row 4w+(lane>>4),
    // 8B chunk (lane&15) within each 64-unit slice.
    const int srowl = (w << 2) + (lane >> 4);   // local row 0..15
    const int scol8 = lane & 15;

    for (int t = 0; t < T_; ++t) {
        const _Float16* hsrc = hbuf + (size_t)(t & 3) * (B_ * H_);
        _Float16*       hdst = hbuf + (size_t)((t + 1) & 3) * (B_ * H_);

        // h-independent prefetch: x fragments + first n-gate block (latency hides under poll)
        half8 ax0 = *(const half8*)(x16 + (((size_t)t << 8) + pi16 + m16) * WS_ + (quad << 3));
        half8 ax1 = *(const half8*)(x16 + (((size_t)t << 8) + pi16 + m16) * WS_ + 32 + (quad << 3));
        half8 bnA[8], bnB[8];
        #pragma unroll
        for (int j = 0; j < 8; ++j) bnA[j] = *(const half8*)(bnp + (j << 5));

        // ---- dataflow staging: poll 16 producer flags in parallel, stage ready slices ----
        {
            unsigned unready = 0xFFFFu;
            const unsigned need = (unsigned)t;
            while (unready) {
                unsigned f = 0xFFFFFFFFu;
                if (lane < 16)
                    f = __hip_atomic_load(bar + (((pi << 4) | lane) << 4),
                                          __ATOMIC_RELAXED, __HIP_MEMORY_SCOPE_AGENT);
                unsigned long long rdy = __ballot(f >= need);
                unsigned todo = unready & (unsigned)(rdy & 0xFFFFull);
                unready &= ~todo;
                while (todo) {
                    int j = __builtin_ctz(todo); todo &= todo - 1;
                    unsigned long long v = __hip_atomic_load(
                        (const unsigned long long*)(hsrc + ((size_t)(pi16 + srowl) << 10) + (j << 6) + (scol8 << 2)),
                        __ATOMIC_RELAXED, __HIP_MEMORY_SCOPE_AGENT);
                    *(unsigned long long*)(&Ash[srowl * 1032 + (j << 6) + (scol8 << 2)]) = v;
                }
                if (unready) __builtin_amdgcn_s_sleep(1);
            }
        }
        __syncthreads();

        floatx4 acc_r  = {b_r,  b_r,  b_r,  b_r };
        floatx4 acc_z  = {b_z,  b_z,  b_z,  b_z };
        floatx4 acc_in = {b_in, b_in, b_in, b_in};
        floatx4 acc_hn = {b_hn, b_hn, b_hn, b_hn};

        // gi = x_t @ Wih^T (K=64, Wih from LDS)
        {
            half8 p0 = *(const half8*)(&Wsh[((w << 4) + m16) * 72        + (quad << 3)]);
            half8 p1 = *(const half8*)(&Wsh[(64 + (w << 4) + m16) * 72   + (quad << 3)]);
            half8 p2 = *(const half8*)(&Wsh[(128 + (w << 4) + m16) * 72  + (quad << 3)]);
            acc_r  = __builtin_amdgcn_mfma_f32_16x16x32_f16(ax0, p0, acc_r,  0, 0, 0);
            acc_z  = __builtin_amdgcn_mfma_f32_16x16x32_f16(ax0, p1, acc_z,  0, 0, 0);
            acc_in = __builtin_amdgcn_mfma_f32_16x16x32_f16(ax0, p2, acc_in, 0, 0, 0);
            half8 q0 = *(const half8*)(&Wsh[((w << 4) + m16) * 72        + 32 + (quad << 3)]);
            half8 q1 = *(const half8*)(&Wsh[(64 + (w << 4) + m16) * 72   + 32 + (quad << 3)]);
            half8 q2 = *(const half8*)(&Wsh[(128 + (w << 4) + m16) * 72  + 32 + (quad << 3)]);
            acc_r  = __builtin_amdgcn_mfma_f32_16x16x32_f16(ax1, q0, acc_r,  0, 0, 0);
            acc_z  = __builtin_amdgcn_mfma_f32_16x16x32_f16(ax1, q1, acc_z,  0, 0, 0);
            acc_in = __builtin_amdgcn_mfma_f32_16x16x32_f16(ax1, q2, acc_in, 0, 0, 0);
        }

        // gh (K=1024): r,z resident; n streamed, software-pipelined 8+8
        #pragma unroll
        for (int blk = 0; blk < 4; ++blk) {
            if (blk < 3) {
                #pragma unroll
                for (int j = 0; j < 8; ++j)
                    bnB[j] = *(const half8*)(bnp + ((((blk + 1) << 3) + j) << 5));
            }
            #pragma unroll
            for (int j = 0; j < 8; ++j) {
                const int c = (blk << 3) + j;
                half8 a = *(const half8*)(&Ash[m16 * 1032 + (c << 5) + (quad << 3)]);
                acc_r  = __builtin_amdgcn_mfma_f32_16x16x32_f16(a, br[c], acc_r,  0, 0, 0);
                acc_z  = __builtin_amdgcn_mfma_f32_16x16x32_f16(a, bz[c], acc_z,  0, 0, 0);
                acc_hn = __builtin_amdgcn_mfma_f32_16x16x32_f16(a, bnA[j], acc_hn, 0, 0, 0);
            }
            #pragma unroll
            for (int j = 0; j < 8; ++j) bnA[j] = bnB[j];
        }

        // GRU nonlinearity; h stays in registers
        float pv[4];
        #pragma unroll
        for (int i = 0; i < 4; ++i) {
            float rg = fast_sigmoid(acc_r[i]);
            float zg = fast_sigmoid(acc_z[i]);
            float ng = fast_tanh(acc_in[i] + rg * acc_hn[i]);
            float hn2 = (1.f - zg) * ng + zg * hreg[i];
            hreg[i] = hn2;
            pv[i] = hn2 * wo_u;
            Hsh[((quad << 2) + i) * 64 + (w << 4) + m16] = (_Float16)hn2;
        }
        __syncthreads();

        // publish h16 ASAP (8B/thread, agent store), then overlap partials work
        {
            unsigned long long hv = *(const unsigned long long*)(&Hsh[tid << 2]);
            __hip_atomic_store(
                (unsigned long long*)(hdst + ((size_t)(pi16 + (tid >> 4)) << 10) + (qi << 6) + ((tid & 15) << 2)),
                hv, __ATOMIC_RELAXED, __HIP_MEMORY_SCOPE_AGENT);
        }
        #pragma unroll
        for (int m = 1; m < 16; m <<= 1) {
            #pragma unroll
            for (int i = 0; i < 4; ++i) pv[i] += __shfl_xor(pv[i], m);
        }
        if (m16 == 0) {
            #pragma unroll
            for (int i = 0; i < 4; ++i)
                partials[((size_t)t * B_ + pi16 + (quad << 2) + i) * 64 + (qi << 2) + w] = pv[i];
        }

        asm volatile("s_waitcnt vmcnt(0)" ::: "memory");  // h slice at coherence point
        __syncthreads();                                   // all 4 waves drained
        if (tid == 0)
            __hip_atomic_store(flag_self, (unsigned)(t + 1),
                               __ATOMIC_RELAXED, __HIP_MEMORY_SCOPE_AGENT);
    }
}

// ---------------- final: out[r,t] = sum_q partials[t,r,q] + bo ----------------
__global__ void out_reduce(const float* __restrict__ partials, const float* __restrict__ bo,
                           float* __restrict__ out) {
    int t = blockIdx.x, r = threadIdx.x;
    const float* p = partials + ((size_t)t * B_ + r) * 64;
    float s = 0.f;
    #pragma unroll
    for (int i = 0; i < 64; ++i) s += p[i];
    out[(size_t)r * T_ + t] = s + bo[0];
}

extern "C" void kernel_launch(void* const* d_in, const int* in_sizes, int n_in,
                              void* d_out, int out_size, void* d_ws, size_t ws_size,
                              hipStream_t stream) {
    const float* lag  = (const float*)d_in[0];
    const float* curr = (const float*)d_in[1];
    const float* W1   = (const float*)d_in[2];
    const float* b1   = (const float*)d_in[3];
    const float* W2   = (const float*)d_in[4];
    const float* b2   = (const float*)d_in[5];
    const float* W3   = (const float*)d_in[6];
    const float* b3   = (const float*)d_in[7];
    const float* Wih  = (const float*)d_in[8];
    const float* Whh  = (const float*)d_in[9];
    const float* bih  = (const float*)d_in[10];
    const float* bhh  = (const float*)d_in[11];
    const float* Wo   = (const float*)d_in[12];
    const float* bo   = (const float*)d_in[13];
    float* out = (float*)d_out;

    char* ws = (char*)d_ws;
    size_t off = 0;
    auto alloc = [&](size_t bytes) -> void* {
        void* p = ws + off;
        off += (bytes + 255) & ~(size_t)255;
        return p;
    };
    _Float16* whh16 = (_Float16*)alloc((size_t)3 * H_ * H_ * 2);
    _Float16* wih16 = (_Float16*)alloc((size_t)3 * H_ * WS_ * 2);
    _Float16* x16   = (_Float16*)alloc((size_t)T_ * B_ * WS_ * 2);
    _Float16* hbuf  = (_Float16*)alloc((size_t)4 * B_ * H_ * 2);   // 4-deep ring
    float* hprev32  = (float*)alloc((size_t)B_ * H_ * 4);
    float* h1       = (float*)alloc((size_t)B_ * 64 * 4);
    float* h2       = (float*)alloc((size_t)B_ * LAT_ * 4);
    float* partials = (float*)alloc((size_t)T_ * B_ * 64 * 4);
    unsigned* bar   = (unsigned*)alloc(16384);

    hipMemsetAsync(bar, 0, 16384, stream);

    int n4;
    n4 = 3 * H_ * H_ / 4;
    cvt_f32_f16_v4<<<(n4 + 255) / 256, 256, 0, stream>>>((const float4*)Whh, (half4*)whh16, n4);
    n4 = 3 * H_ * WS_ / 4;
    cvt_f32_f16_v4<<<(n4 + 255) / 256, 256, 0, stream>>>((const float4*)Wih, (half4*)wih16, n4);
    n4 = T_ * B_ * WS_ / 4;
    cvt_f32_f16_v4<<<(n4 + 255) / 256, 256, 0, stream>>>((const float4*)curr, (half4*)x16, n4);

    enc12<<<B_, 64, 0, stream>>>(lag, W1, b1, h1, LAG_);
    enc12<<<B_, LAT_, 0, stream>>>(h1, W2, b2, h2, 64);
    enc3<<<B_, 256, 0, stream>>>(h2, W3, b3, hprev32, hbuf);   // h0 -> ring slot 0

    gru_persistent<<<dim3(256), dim3(256), 0, stream>>>(
        hbuf, hprev32, whh16, wih16, x16, bih, bhh, Wo, partials, bar);

    out_reduce<<<T_, B_, 0, stream>>>(partials, bo, out);
}

// Round 9
// 812.339 us; speedup vs baseline: 2.8141x; 1.8652x over previous
//
#include <hip/hip_runtime.h>
#include <hip/hip_bf16.h>
#include <cstdint>
#include <cstddef>

typedef _Float16 half8 __attribute__((ext_vector_type(8)));
typedef _Float16 half4 __attribute__((ext_vector_type(4)));
typedef float floatx4 __attribute__((ext_vector_type(4)));
typedef unsigned long long u64;

#define B_ 256
#define T_ 168
#define H_ 1024
#define WS_ 64
#define LAG_ 168
#define LAT_ 128

__device__ __forceinline__ float fast_sigmoid(float x) {
    return __builtin_amdgcn_rcpf(1.f + __expf(-x));
}
__device__ __forceinline__ float fast_tanh(float x) {
    return 1.f - 2.f * __builtin_amdgcn_rcpf(__expf(2.f * x) + 1.f);
}

// ---------------- fp32 -> fp16 conversion ----------------
__global__ void cvt_f32_f16_v4(const float4* __restrict__ src, half4* __restrict__ dst, int n4) {
    int i = blockIdx.x * blockDim.x + threadIdx.x;
    if (i < n4) {
        float4 v = src[i];
        half4 o;
        o[0] = (_Float16)v.x; o[1] = (_Float16)v.y;
        o[2] = (_Float16)v.z; o[3] = (_Float16)v.w;
        dst[i] = o;
    }
}

// ---------------- encoder layers 1,2 ----------------
__global__ void enc12(const float* __restrict__ in, const float* __restrict__ W,
                      const float* __restrict__ bias, float* __restrict__ outb, int infeat) {
    int r = blockIdx.x, j = threadIdx.x;
    const float* row = in + (size_t)r * infeat;
    const float* w   = W  + (size_t)j * infeat;
    float s = bias[j];
    for (int k = 0; k < infeat; ++k) s += row[k] * w[k];
    outb[(size_t)r * blockDim.x + j] = (s >= 0.f) ? s : 0.01f * s;
}

// ---------------- encoder layer 3 ----------------
__global__ void enc3(const float* __restrict__ h2, const float* __restrict__ W3,
                     const float* __restrict__ b3, float* __restrict__ hprev32,
                     _Float16* __restrict__ h0f16) {
    __shared__ float s[LAT_];
    int r = blockIdx.x;
    if (threadIdx.x < LAT_) s[threadIdx.x] = h2[(size_t)r * LAT_ + threadIdx.x];
    __syncthreads();
    for (int j = threadIdx.x; j < H_; j += 256) {
        const float* w = W3 + (size_t)j * LAT_;
        float acc = b3[j];
        #pragma unroll 8
        for (int k = 0; k < LAT_; ++k) acc += s[k] * w[k];
        hprev32[(size_t)r * H_ + j] = acc;
        h0f16[(size_t)r * H_ + j]   = (_Float16)acc;
    }
}

// ---------------- persistent GRU: phase-pipelined exchange ----------------
// 256 WGs x 256 thr: pi=blk&15 rows [16pi,+16); qi=blk>>4 units [64qi,+64).
// r,z Whh resident (AGPR-backed); n streamed 8+8. Per-WAVE flags (1024): each
// wave publishes its 16-unit slice + flag with NO barrier. Consumer: K-loop in
// 4 phases of 256 units; poll caches ready-bits for all 64 producer waves in one
// ballot register; phase g+1 staged (agent 8B loads -> LDS) while phase g MFMAs
// run. R9 fix: __threadfence_block() between Hsh transpose-write (f16) and
// publish-read (u64) — R8 lacked it and the compiler (TBAA: f16 vs u64 don't
// alias) could hoist the read above the writes -> published uninitialized LDS
// (NaN) into the h ring. Every other cross-type LDS access crosses a
// __syncthreads(); this was the only naked one.
__global__ __launch_bounds__(256, 1) void gru_persistent(
    _Float16* __restrict__ hbuf,
    const float* __restrict__ hprev32, const _Float16* __restrict__ whh16,
    const _Float16* __restrict__ wih16, const _Float16* __restrict__ x16,
    const float* __restrict__ bih, const float* __restrict__ bhh,
    const float* __restrict__ Wo, float* __restrict__ partials,
    unsigned* __restrict__ bar)
{
    __shared__ __align__(16) _Float16 Ash[16 * 1032];
    __shared__ __align__(16) _Float16 Wsh[192 * 72];
    __shared__ __align__(16) _Float16 Hsh[4 * 256];   // per-wave 16x16 transpose segments

    const int tid  = threadIdx.x;
    const int w    = tid >> 6;
    const int lane = tid & 63;
    const int m16  = lane & 15;
    const int quad = lane >> 4;
    const int pi   = blockIdx.x & 15;
    const int qi   = blockIdx.x >> 4;
    const int pi16 = pi << 4;
    const int u    = (qi << 6) + (w << 4) + m16;

    // Wih slice -> LDS (once)
    for (int idx = tid; idx < 1536; idx += 256) {
        int rowl = idx >> 3, ch = idx & 7;
        int g = rowl >> 6, ru = rowl & 63;
        *(uint4*)(&Wsh[rowl * 72 + (ch << 3)]) =
            *(const uint4*)(wih16 + (size_t)(((g << 10) + (qi << 6) + ru) << 6) + (ch << 3));
    }

    // Resident Whh: r,z gates (AGPR-backed)
    half8 br[32], bz[32];
    {
        const _Float16* p0 = whh16 + ((size_t)u << 10) + (quad << 3);
        const _Float16* p1 = whh16 + ((size_t)(H_ + u) << 10) + (quad << 3);
        #pragma unroll
        for (int c = 0; c < 32; ++c) br[c] = *(const half8*)(p0 + (c << 5));
        #pragma unroll
        for (int c = 0; c < 32; ++c) bz[c] = *(const half8*)(p1 + (c << 5));
    }
    const _Float16* bnp = whh16 + ((size_t)(2 * H_ + u) << 10) + (quad << 3);

    const float b_r  = bih[u]          + bhh[u];
    const float b_z  = bih[H_ + u]     + bhh[H_ + u];
    const float b_in = bih[2 * H_ + u];
    const float b_hn = bhh[2 * H_ + u];
    const float wo_u = Wo[u];

    float hreg[4];
    #pragma unroll
    for (int i = 0; i < 4; ++i)
        hreg[i] = hprev32[((size_t)(pi16 + (quad << 2) + i) << 10) + u];

    __syncthreads();

    // per-wave flag lines (64B apart)
    unsigned* flag_self       = bar + ((((pi << 4) | qi) << 2 | w) << 4);
    const unsigned* flag_peer = bar + ((((pi << 4) | (lane >> 2)) << 2 | (lane & 3)) << 4);
    const int srow = tid >> 4;     // staging: this thread's local row
    const int sch  = tid & 15;     // 32B chunk (16 units)
    const int prow = lane >> 2;    // publish: row, 8B chunk
    const int pc4  = lane & 3;

    for (int t = 0; t < T_; ++t) {
        const _Float16* hsrc = hbuf + (size_t)(t & 3) * (B_ * H_);
        _Float16*       hdst = hbuf + (size_t)((t + 1) & 3) * (B_ * H_);

        // h-independent prefetch (flies under the poll)
        half8 ax0 = *(const half8*)(x16 + (((size_t)t << 8) + pi16 + m16) * WS_ + (quad << 3));
        half8 ax1 = *(const half8*)(x16 + (((size_t)t << 8) + pi16 + m16) * WS_ + 32 + (quad << 3));
        half8 bnA[8], bnB[8];
        #pragma unroll
        for (int j = 0; j < 8; ++j) bnA[j] = *(const half8*)(bnp + (j << 5));

        const unsigned need = (unsigned)t;
        u64 rdy = 0;

        // wait phase 0 (lanes 0..15 = producer waves of units [0,256))
        while ((rdy & 0xFFFFull) != 0xFFFFull) {
            unsigned f = __hip_atomic_load(flag_peer, __ATOMIC_RELAXED, __HIP_MEMORY_SCOPE_AGENT);
            rdy |= __ballot(f >= need);
            if ((rdy & 0xFFFFull) != 0xFFFFull) __builtin_amdgcn_s_sleep(1);
        }
        // issue phase-0 A loads
        u64 va0, va1, va2, va3;
        {
            const _Float16* s = hsrc + ((size_t)(pi16 + srow) << 10) + (sch << 4);
            va0 = __hip_atomic_load((const u64*)(s + 0),  __ATOMIC_RELAXED, __HIP_MEMORY_SCOPE_AGENT);
            va1 = __hip_atomic_load((const u64*)(s + 4),  __ATOMIC_RELAXED, __HIP_MEMORY_SCOPE_AGENT);
            va2 = __hip_atomic_load((const u64*)(s + 8),  __ATOMIC_RELAXED, __HIP_MEMORY_SCOPE_AGENT);
            va3 = __hip_atomic_load((const u64*)(s + 12), __ATOMIC_RELAXED, __HIP_MEMORY_SCOPE_AGENT);
        }

        floatx4 acc_r  = {b_r,  b_r,  b_r,  b_r };
        floatx4 acc_z  = {b_z,  b_z,  b_z,  b_z };
        floatx4 acc_in = {b_in, b_in, b_in, b_in};
        floatx4 acc_hn = {b_hn, b_hn, b_hn, b_hn};

        // gi = x_t @ Wih^T (fills the phase-0 stage window)
        {
            half8 p0 = *(const half8*)(&Wsh[((w << 4) + m16) * 72        + (quad << 3)]);
            half8 p1 = *(const half8*)(&Wsh[(64 + (w << 4) + m16) * 72   + (quad << 3)]);
            half8 p2 = *(const half8*)(&Wsh[(128 + (w << 4) + m16) * 72  + (quad << 3)]);
            acc_r  = __builtin_amdgcn_mfma_f32_16x16x32_f16(ax0, p0, acc_r,  0, 0, 0);
            acc_z  = __builtin_amdgcn_mfma_f32_16x16x32_f16(ax0, p1, acc_z,  0, 0, 0);
            acc_in = __builtin_amdgcn_mfma_f32_16x16x32_f16(ax0, p2, acc_in, 0, 0, 0);
            half8 q0 = *(const half8*)(&Wsh[((w << 4) + m16) * 72        + 32 + (quad << 3)]);
            half8 q1 = *(const half8*)(&Wsh[(64 + (w << 4) + m16) * 72   + 32 + (quad << 3)]);
            half8 q2 = *(const half8*)(&Wsh[(128 + (w << 4) + m16) * 72  + 32 + (quad << 3)]);
            acc_r  = __builtin_amdgcn_mfma_f32_16x16x32_f16(ax1, q0, acc_r,  0, 0, 0);
            acc_z  = __builtin_amdgcn_mfma_f32_16x16x32_f16(ax1, q1, acc_z,  0, 0, 0);
            acc_in = __builtin_amdgcn_mfma_f32_16x16x32_f16(ax1, q2, acc_in, 0, 0, 0);
        }

        // 4 phases: write staged A -> barrier -> poll+issue next phase -> MFMA this phase
        #pragma unroll
        for (int g = 0; g < 4; ++g) {
            {
                _Float16* d = &Ash[srow * 1032 + (g << 8) + (sch << 4)];
                *(u64*)(d + 0)  = va0;
                *(u64*)(d + 4)  = va1;
                *(u64*)(d + 8)  = va2;
                *(u64*)(d + 12) = va3;
            }
            __syncthreads();
            if (g < 3) {
                const u64 mask = 0xFFFFull << ((g + 1) << 4);
                while ((rdy & mask) != mask) {
                    unsigned f = __hip_atomic_load(flag_peer, __ATOMIC_RELAXED, __HIP_MEMORY_SCOPE_AGENT);
                    rdy |= __ballot(f >= need);
                    if ((rdy & mask) != mask) __builtin_amdgcn_s_sleep(1);
                }
                const _Float16* s = hsrc + ((size_t)(pi16 + srow) << 10) + ((g + 1) << 8) + (sch << 4);
                va0 = __hip_atomic_load((const u64*)(s + 0),  __ATOMIC_RELAXED, __HIP_MEMORY_SCOPE_AGENT);
                va1 = __hip_atomic_load((const u64*)(s + 4),  __ATOMIC_RELAXED, __HIP_MEMORY_SCOPE_AGENT);
                va2 = __hip_atomic_load((const u64*)(s + 8),  __ATOMIC_RELAXED, __HIP_MEMORY_SCOPE_AGENT);
                va3 = __hip_atomic_load((const u64*)(s + 12), __ATOMIC_RELAXED, __HIP_MEMORY_SCOPE_AGENT);
                #pragma unroll
                for (int j = 0; j < 8; ++j)
                    bnB[j] = *(const half8*)(bnp + ((((g + 1) << 3) + j) << 5));
            }
            #pragma unroll
            for (int j = 0; j < 8; ++j) {
                const int c = (g << 3) + j;
                half8 a = *(const half8*)(&Ash[m16 * 1032 + (c << 5) + (quad << 3)]);
                acc_r  = __builtin_amdgcn_mfma_f32_16x16x32_f16(a, br[c], acc_r,  0, 0, 0);
                acc_z  = __builtin_amdgcn_mfma_f32_16x16x32_f16(a, bz[c], acc_z,  0, 0, 0);
                acc_hn = __builtin_amdgcn_mfma_f32_16x16x32_f16(a, bnA[j], acc_hn, 0, 0, 0);
            }
            if (g < 3) {
                #pragma unroll
                for (int j = 0; j < 8; ++j) bnA[j] = bnB[j];
            }
        }

        // epilogue (fully per-wave; NO barrier before publish)
        float pv[4];
        #pragma unroll
        for (int i = 0; i < 4; ++i) {
            float rg = fast_sigmoid(acc_r[i]);
            float zg = fast_sigmoid(acc_z[i]);
            float ng = fast_tanh(acc_in[i] + rg * acc_hn[i]);
            float hn2 = (1.f - zg) * ng + zg * hreg[i];
            hreg[i] = hn2;
            pv[i] = hn2 * wo_u;
            Hsh[(w << 8) + ((quad << 2) + i) * 16 + m16] = (_Float16)hn2;
        }
        // R9 FIX: order the f16 Hsh writes before the u64 read (compiler + DS pipe)
        __threadfence_block();
        {
            u64 hv = *(const u64*)(&Hsh[(w << 8) + prow * 16 + (pc4 << 2)]);
            __hip_atomic_store(
                (u64*)(hdst + ((size_t)(pi16 + prow) << 10) + (qi << 6) + (w << 4) + (pc4 << 2)),
                hv, __ATOMIC_RELAXED, __HIP_MEMORY_SCOPE_AGENT);
        }
        asm volatile("s_waitcnt vmcnt(0)" ::: "memory");  // this wave's publish drained
        if (lane == 0)
            __hip_atomic_store(flag_self, (unsigned)(t + 1),
                               __ATOMIC_RELAXED, __HIP_MEMORY_SCOPE_AGENT);
        #pragma unroll
        for (int m = 1; m < 16; m <<= 1) {
            #pragma unroll
            for (int i = 0; i < 4; ++i) pv[i] += __shfl_xor(pv[i], m);
        }
        if (m16 == 0) {
            #pragma unroll
            for (int i = 0; i < 4; ++i)
                partials[((size_t)t * B_ + pi16 + (quad << 2) + i) * 64 + (qi << 2) + w] = pv[i];
        }
    }
}

// ---------------- final reduce ----------------
__global__ void out_reduce(const float* __restrict__ partials, const float* __restrict__ bo,
                           float* __restrict__ out) {
    int t = blockIdx.x, r = threadIdx.x;
    const float* p = partials + ((size_t)t * B_ + r) * 64;
    float s = 0.f;
    #pragma unroll
    for (int i = 0; i < 64; ++i) s += p[i];
    out[(size_t)r * T_ + t] = s + bo[0];
}

extern "C" void kernel_launch(void* const* d_in, const int* in_sizes, int n_in,
                              void* d_out, int out_size, void* d_ws, size_t ws_size,
                              hipStream_t stream) {
    const float* lag  = (const float*)d_in[0];
    const float* curr = (const float*)d_in[1];
    const float* W1   = (const float*)d_in[2];
    const float* b1   = (const float*)d_in[3];
    const float* W2   = (const float*)d_in[4];
    const float* b2   = (const float*)d_in[5];
    const float* W3   = (const float*)d_in[6];
    const float* b3   = (const float*)d_in[7];
    const float* Wih  = (const float*)d_in[8];
    const float* Whh  = (const float*)d_in[9];
    const float* bih  = (const float*)d_in[10];
    const float* bhh  = (const float*)d_in[11];
    const float* Wo   = (const float*)d_in[12];
    const float* bo   = (const float*)d_in[13];
    float* out = (float*)d_out;

    char* ws = (char*)d_ws;
    size_t off = 0;
    auto alloc = [&](size_t bytes) -> void* {
        void* p = ws + off;
        off += (bytes + 255) & ~(size_t)255;
        return p;
    };
    _Float16* whh16 = (_Float16*)alloc((size_t)3 * H_ * H_ * 2);
    _Float16* wih16 = (_Float16*)alloc((size_t)3 * H_ * WS_ * 2);
    _Float16* x16   = (_Float16*)alloc((size_t)T_ * B_ * WS_ * 2);
    _Float16* hbuf  = (_Float16*)alloc((size_t)4 * B_ * H_ * 2);
    float* hprev32  = (float*)alloc((size_t)B_ * H_ * 4);
    float* h1       = (float*)alloc((size_t)B_ * 64 * 4);
    float* h2       = (float*)alloc((size_t)B_ * LAT_ * 4);
    float* partials = (float*)alloc((size_t)T_ * B_ * 64 * 4);
    unsigned* bar   = (unsigned*)alloc(81920);

    hipMemsetAsync(bar, 0, 81920, stream);

    int n4;
    n4 = 3 * H_ * H_ / 4;
    cvt_f32_f16_v4<<<(n4 + 255) / 256, 256, 0, stream>>>((const float4*)Whh, (half4*)whh16, n4);
    n4 = 3 * H_ * WS_ / 4;
    cvt_f32_f16_v4<<<(n4 + 255) / 256, 256, 0, stream>>>((const float4*)Wih, (half4*)wih16, n4);
    n4 = T_ * B_ * WS_ / 4;
    cvt_f32_f16_v4<<<(n4 + 255) / 256, 256, 0, stream>>>((const float4*)curr, (half4*)x16, n4);

    enc12<<<B_, 64, 0, stream>>>(lag, W1, b1, h1, LAG_);
    enc12<<<B_, LAT_, 0, stream>>>(h1, W2, b2, h2, 64);
    enc3<<<B_, 256, 0, stream>>>(h2, W3, b3, hprev32, hbuf);

    gru_persistent<<<dim3(256), dim3(256), 0, stream>>>(
        hbuf, hprev32, whh16, wih16, x16, bih, bhh, Wo, partials, bar);

    out_reduce<<<T_, B_, 0, stream>>>(partials, bo, out);
}